// Round 12
// baseline (376.464 us; speedup 1.0000x reference)
//
#include <hip/hip_runtime.h>
#include <math.h>

#define F_IN 32
#define NH 8
#define C1 8
#define D1 64
#define NEG 0.2f
#define LOG2E 1.44269504088896f
#define SHBIAS (-20.0f * LOG2E)   // fixed softmax shift (shift-invariant, avoids overflow)
#define SC_KI 2                   // iv4 loads per thread per array in scatter
#define SC_EDGES (256 * 4 * SC_KI)  // 2048 edges per scatter block
#define NX 8                      // per-XCD counter replicas

typedef int iv4 __attribute__((ext_vector_type(4)));
typedef unsigned short ushort_t;

__device__ __forceinline__ ushort_t f2bf(float f) {   // RNE float->bf16
    unsigned int b = __float_as_uint(f);
    return (ushort_t)((b + 0x7FFF + ((b >> 16) & 1)) >> 16);
}
__device__ __forceinline__ float bf2f(ushort_t u) {
    return __uint_as_float(((unsigned int)u) << 16);
}

__device__ __forceinline__ int get_xcd() {
    int x;
    asm volatile("s_getreg_b32 %0, hwreg(HW_REG_XCC_ID)" : "=s"(x));
    return x & (NX - 1);
}

// ---------------- CSR build ----------------

// cnt replicas: replica r occupies cnt[r*N .. r*N+N). Replica 0 inits to 1
// (reserves slot 0 of each node segment for the self-loop).
__global__ void k_init_cnt(int* __restrict__ cnt, int N, int total) {
    int i = blockIdx.x * blockDim.x + threadIdx.x;
    int stride = gridDim.x * blockDim.x;
    for (; i < total; i += stride) cnt[i] = (i < N) ? 1 : 0;
}

// hist + rank capture into the executing XCD's private replica: lines stay
// exclusive to one L2 -> atomics avoid the cross-XCD coherence round-trip
// (R10/R11: dense and line-padded both ~21G atomics/s -> migration-bound).
// rank stores (slot<<3)|xcd so the scatter can reconstruct the position.
__device__ __forceinline__ void hist_body(const int* __restrict__ ei, int E4,
                                          int* __restrict__ cnt, int* __restrict__ rank,
                                          int N, int b) {
    int i = b * 256 + threadIdx.x;
    if (i >= E4) return;
    int xcd = get_xcd();
    int* cr = cnt + xcd * N;
    iv4 d = __builtin_nontemporal_load((const iv4*)(ei) + E4 + i);
    iv4 r;
    r.x = (atomicAdd(&cr[d.x], 1) << 3) | xcd;
    r.y = (atomicAdd(&cr[d.y], 1) << 3) | xcd;
    r.z = (atomicAdd(&cr[d.z], 1) << 3) | xcd;
    r.w = (atomicAdd(&cr[d.w], 1) << 3) | xcd;
    __builtin_nontemporal_store(r, (iv4*)rank + i);
}

// node1: h = x@W1 (stored bf16), attention logits a_s/a_d (f32)
__device__ __forceinline__ void node1_body(const float* __restrict__ x, const float* __restrict__ W1,
                                           const float* __restrict__ as1, const float* __restrict__ ad1,
                                           ushort_t* __restrict__ h1b, float* __restrict__ a_s,
                                           float* __restrict__ a_d, int N, int b) {
    __shared__ float sW[F_IN * D1];
    __shared__ float sA[2 * D1];
    for (int i = threadIdx.x; i < F_IN * D1; i += blockDim.x) sW[i] = W1[i];
    if (threadIdx.x < 2 * D1)
        sA[threadIdx.x] = (threadIdx.x < D1) ? as1[threadIdx.x] : ad1[threadIdx.x - D1];
    __syncthreads();
    int t = b * blockDim.x + threadIdx.x;
    int n = t >> 3, h = t & 7;
    if (n >= N) return;
    float xr[F_IN];
    const float4* xv = (const float4*)(x + n * F_IN);
#pragma unroll
    for (int k = 0; k < F_IN / 4; ++k) {
        float4 v = xv[k];
        xr[4 * k] = v.x; xr[4 * k + 1] = v.y; xr[4 * k + 2] = v.z; xr[4 * k + 3] = v.w;
    }
    float acc[C1];
#pragma unroll
    for (int c = 0; c < C1; ++c) acc[c] = 0.0f;
#pragma unroll
    for (int k = 0; k < F_IN; ++k) {
        float xk = xr[k];
#pragma unroll
        for (int c = 0; c < C1; ++c) acc[c] = fmaf(xk, sW[k * D1 + h * C1 + c], acc[c]);
    }
    float s_ = 0.0f, d_ = 0.0f;
    unsigned int w[4];
#pragma unroll
    for (int c = 0; c < C1; ++c) {
        s_ = fmaf(acc[c], sA[h * C1 + c], s_);
        d_ = fmaf(acc[c], sA[D1 + h * C1 + c], d_);
    }
#pragma unroll
    for (int k = 0; k < 4; ++k)
        w[k] = (unsigned int)f2bf(acc[2 * k]) | ((unsigned int)f2bf(acc[2 * k + 1]) << 16);
    iv4 wv = {(int)w[0], (int)w[1], (int)w[2], (int)w[3]};
    *(iv4*)(h1b + (size_t)n * D1 + h * C1) = wv;   // 16B aligned vector store
    a_s[n * NH + h] = s_;
    a_d[n * NH + h] = d_;
}

// fused: hist (atomic-latency-bound, ~idle VALU) || node1 (pure compute)
__global__ void __launch_bounds__(256)
k_hist_node1(const int* __restrict__ ei, int E4,
             int* __restrict__ cnt, int* __restrict__ rank,
             const float* __restrict__ x, const float* __restrict__ W1,
             const float* __restrict__ as1, const float* __restrict__ ad1,
             ushort_t* __restrict__ h1b, float* __restrict__ a_s, float* __restrict__ a_d,
             int N, int nH) {
    int b = blockIdx.x;
    if (b < nH) hist_body(ei, E4, cnt, rank, N, b);
    else        node1_body(x, W1, as1, ad1, h1b, a_s, a_d, N, b - nH);
}

// scan over 800k (node-major, xcd-minor): thread t of block b owns node
// d = b*256+t, loads its 8 replica counts (coalesced per replica), scans.
__global__ void __launch_bounds__(256)
k_scan_block8(const int* __restrict__ cnt, int* __restrict__ ptrtmp8,
              int* __restrict__ bsum, int N) {
    __shared__ int s[256];
    int d = blockIdx.x * 256 + threadIdx.x;
    int c[NX], pre[NX];
    int run = 0;
#pragma unroll
    for (int xx = 0; xx < NX; ++xx) {
        c[xx] = (d < N) ? cnt[xx * N + d] : 0;
        pre[xx] = run;
        run += c[xx];
    }
    s[threadIdx.x] = run;
    __syncthreads();
#pragma unroll
    for (int off = 1; off < 256; off <<= 1) {
        int t = (threadIdx.x >= off) ? s[threadIdx.x - off] : 0;
        __syncthreads();
        s[threadIdx.x] += t;
        __syncthreads();
    }
    int excl = s[threadIdx.x] - run;
    if (d < N) {
#pragma unroll
        for (int xx = 0; xx < NX; ++xx) ptrtmp8[d * NX + xx] = excl + pre[xx];
    }
    if (threadIdx.x == 255) bsum[blockIdx.x] = s[255];
}

__global__ void k_scan_bsums(int* __restrict__ bsum, int nb) {
    __shared__ int s[512];
    int t = threadIdx.x;
    s[t] = (t < nb) ? bsum[t] : 0;
    __syncthreads();
#pragma unroll
    for (int off = 1; off < 512; off <<= 1) {
        int v = (t >= off) ? s[t - off] : 0;
        __syncthreads();
        s[t] += v;
        __syncthreads();
    }
    if (t < nb) bsum[t] = (t == 0) ? 0 : s[t - 1];
}

// each scan block covered 256 nodes = 2048 flat elements -> bsum index i>>11
__global__ void k_scan_finalize(const int* __restrict__ ptrtmp8, const int* __restrict__ bsum,
                                int* __restrict__ ptr8, int N8, int Et) {
    int i = blockIdx.x * blockDim.x + threadIdx.x;
    if (i > N8) return;
    ptr8[i] = (i < N8) ? (ptrtmp8[i] + bsum[i >> 11]) : Et;
}

// atomic-free scatter: pos = ptr8[d*8 + (rank&7)] + (rank>>3); self-loop fill fused
__device__ __forceinline__ void scatter_body(const int* __restrict__ ei, int E4,
                                             const int* __restrict__ rank,
                                             const int* __restrict__ ptr8,
                                             int* __restrict__ srcs, int b) {
    const iv4* s4 = (const iv4*)ei;
    const iv4* d4 = s4 + E4;
    const iv4* r4 = (const iv4*)rank;
    int base = b * (SC_EDGES / 4) + threadIdx.x;
    iv4 dv[SC_KI], sv[SC_KI], rv[SC_KI];
#pragma unroll
    for (int k = 0; k < SC_KI; ++k) {
        int idx = base + k * 256;
        if (idx < E4) {
            dv[k] = __builtin_nontemporal_load(d4 + idx);
            sv[k] = __builtin_nontemporal_load(s4 + idx);
            rv[k] = __builtin_nontemporal_load(r4 + idx);
        } else {
            dv[k] = (iv4){-1, -1, -1, -1};
            sv[k] = (iv4){0, 0, 0, 0};
            rv[k] = (iv4){0, 0, 0, 0};
        }
    }
#pragma unroll
    for (int k = 0; k < SC_KI; ++k) {
        int dd[4] = {dv[k].x, dv[k].y, dv[k].z, dv[k].w};
        int ss[4] = {sv[k].x, sv[k].y, sv[k].z, sv[k].w};
        int rr[4] = {rv[k].x, rv[k].y, rv[k].z, rv[k].w};
#pragma unroll
        for (int u = 0; u < 4; ++u) {
            int d = dd[u];
            if (d >= 0) srcs[ptr8[(d << 3) + (rr[u] & 7)] + (rr[u] >> 3)] = ss[u];
        }
    }
}

__global__ void __launch_bounds__(256)
k_scatter(const int* __restrict__ ei, int E4,
          const int* __restrict__ rank, const int* __restrict__ ptr8,
          int* __restrict__ srcs, int N, int nSc) {
    int b = blockIdx.x;
    if (b < nSc) {
        scatter_body(ei, E4, rank, ptr8, srcs, b);
    } else {
        int i = (b - nSc) * 256 + threadIdx.x;
        if (i < N) srcs[ptr8[i << 3]] = i;   // self-loop in reserved slot 0
    }
}

// ---------------- layer 1: wave per node, transposed logit phase ----------------

__device__ __forceinline__ float lrelu(float e) { return e > 0.0f ? e : NEG * e; }

__global__ void __launch_bounds__(256)
k_gat1(const int* __restrict__ ptr8, const int* __restrict__ srcs,
       const float* __restrict__ a_s, const float* __restrict__ a_d,
       const ushort_t* __restrict__ h1b,
       const float* __restrict__ b1, const float* __restrict__ W2,
       const float* __restrict__ as2, const float* __restrict__ ad2,
       float* __restrict__ h2, float* __restrict__ a_s2o, float* __restrict__ a_d2o,
       int N) {
    int n = (blockIdx.x * blockDim.x + threadIdx.x) >> 6;
    if (n >= N) return;
    int l = threadIdx.x & 63;
    int j = l >> 3;          // edge slot (logit phase)
    int h = l & 7;           // head (logit phase)
    int start = ptr8[n << 3], end = ptr8[(n + 1) << 3];
    float ad = a_d[n * NH + h];
    const ushort_t* hb = h1b + l;    // lane-fixed offset into bf16 h rows
    float den = 0.0f, acc = 0.0f;
    for (int base = start; base < end; base += 8) {
        int idxl = base + j;
        bool valid = idxl < end;
        if (!valid) idxl = end - 1;
        int s = srcs[idxl];                         // 8 consecutive ints, group-shared
        float as = a_s[(s << 3) + h];               // 8x32B contiguous segments
        float ex = exp2f(fmaf(lrelu(as + ad), LOG2E, SHBIAS));
        if (!valid) ex = 0.0f;
        den += ex;                                   // per-lane (j,h) partial
        int s0 = __builtin_amdgcn_readlane(s, 0),  s1 = __builtin_amdgcn_readlane(s, 8);
        int s2 = __builtin_amdgcn_readlane(s, 16), s3 = __builtin_amdgcn_readlane(s, 24);
        int s4 = __builtin_amdgcn_readlane(s, 32), s5 = __builtin_amdgcn_readlane(s, 40);
        int s6 = __builtin_amdgcn_readlane(s, 48), s7 = __builtin_amdgcn_readlane(s, 56);
        float g0 = bf2f(hb[s0 << 6]), g1 = bf2f(hb[s1 << 6]);
        float g2 = bf2f(hb[s2 << 6]), g3 = bf2f(hb[s3 << 6]);
        float g4 = bf2f(hb[s4 << 6]), g5 = bf2f(hb[s5 << 6]);
        float g6 = bf2f(hb[s6 << 6]), g7 = bf2f(hb[s7 << 6]);
        int bl = l >> 3;
        float e0 = __shfl(ex, 0 + bl, 64),  e1 = __shfl(ex, 8 + bl, 64);
        float e2 = __shfl(ex, 16 + bl, 64), e3 = __shfl(ex, 24 + bl, 64);
        float e4 = __shfl(ex, 32 + bl, 64), e5 = __shfl(ex, 40 + bl, 64);
        float e6 = __shfl(ex, 48 + bl, 64), e7 = __shfl(ex, 56 + bl, 64);
        acc = fmaf(e0, g0, acc); acc = fmaf(e1, g1, acc);
        acc = fmaf(e2, g2, acc); acc = fmaf(e3, g3, acc);
        acc = fmaf(e4, g4, acc); acc = fmaf(e5, g5, acc);
        acc = fmaf(e6, g6, acc); acc = fmaf(e7, g7, acc);
    }
    den += __shfl_xor(den, 8, 64);
    den += __shfl_xor(den, 16, 64);
    den += __shfl_xor(den, 32, 64);
    den = __shfl(den, l >> 3, 64);   // re-layout: lane l gets den[h = l>>3]
    float v = acc / den + b1[l];
    v = v > 0.0f ? v : expm1f(v);    // ELU
    float r0 = v * W2[l * 2 + 0];
    float r1 = v * W2[l * 2 + 1];
#pragma unroll
    for (int off = 32; off; off >>= 1) {
        r0 += __shfl_xor(r0, off, 64);
        r1 += __shfl_xor(r1, off, 64);
    }
    if (l == 0) {
        h2[n * 2 + 0] = r0;
        h2[n * 2 + 1] = r1;
        a_s2o[n] = r0 * as2[0] + r1 * as2[1];
        a_d2o[n] = r0 * ad2[0] + r1 * ad2[1];
    }
}

// ---------------- layer 2: 16 lanes per node (avg degree ~33) ----------------

__global__ void k_gat2(const int* __restrict__ ptr8, const int* __restrict__ srcs,
                       const float* __restrict__ a_s2, const float* __restrict__ a_d2,
                       const float* __restrict__ h2, const float* __restrict__ b2,
                       float* __restrict__ out, int N) {
    int t = blockIdx.x * blockDim.x + threadIdx.x;
    int n = t >> 4;
    if (n >= N) return;
    int l = threadIdx.x & 15;
    int start = ptr8[n << 3], end = ptr8[(n + 1) << 3];
    float ad = a_d2[n];
    float den = 0.0f, a0 = 0.0f, a1 = 0.0f;
    for (int idx = start + l; idx < end; idx += 16) {
        int s = srcs[idx];
        float ex = exp2f(fmaf(lrelu(a_s2[s] + ad), LOG2E, SHBIAS));
        float2 hv = *(const float2*)(h2 + s * 2);
        den += ex;
        a0 = fmaf(ex, hv.x, a0);
        a1 = fmaf(ex, hv.y, a1);
    }
#pragma unroll
    for (int off = 8; off; off >>= 1) {
        den += __shfl_xor(den, off, 16);
        a0  += __shfl_xor(a0, off, 16);
        a1  += __shfl_xor(a1, off, 16);
    }
    if (l == 0) {
        float inv = 1.0f / den;
        float o0 = a0 * inv + b2[0];
        float o1 = a1 * inv + b2[1];
        float mx = fmaxf(o0, o1);
        float lse = mx + logf(__expf(o0 - mx) + __expf(o1 - mx));
        out[n * 2 + 0] = o0 - lse;
        out[n * 2 + 1] = o1 - lse;
    }
}

extern "C" void kernel_launch(void* const* d_in, const int* in_sizes, int n_in,
                              void* d_out, int out_size, void* d_ws, size_t ws_size,
                              hipStream_t stream) {
    const float* x   = (const float*)d_in[0];
    const int*   ei  = (const int*)d_in[1];
    const float* W1  = (const float*)d_in[2];
    const float* as1 = (const float*)d_in[3];
    const float* ad1 = (const float*)d_in[4];
    const float* b1  = (const float*)d_in[5];
    const float* W2  = (const float*)d_in[6];
    const float* as2 = (const float*)d_in[7];
    const float* ad2 = (const float*)d_in[8];
    const float* b2  = (const float*)d_in[9];
    float* out = (float*)d_out;

    const int N  = in_sizes[0] / F_IN;   // 100000
    const int E  = in_sizes[1] / 2;      // 3200000
    const int E4 = E / 4;                // 800000
    const int Et = E + N;
    const int nb = (N + 255) / 256;      // 391 scan blocks (<=512)
    const int N8 = N * NX;

    char* p = (char*)d_ws;
    ushort_t* h1b = (ushort_t*)p; p += (size_t)N * D1 * 2;   // bf16 h1
    float* a_s1 = (float*)p; p += (size_t)N * NH * 4;
    float* a_d1 = (float*)p; p += (size_t)N * NH * 4;
    float* h2   = (float*)p; p += (size_t)N * 2 * 4;
    float* a_s2 = (float*)p; p += (size_t)N * 4;
    float* a_d2 = (float*)p; p += (size_t)N * 4;
    int* cnt    = (int*)p;   p += (size_t)N8 * 4;            // 8 XCD replicas
    int* ptrtmp = (int*)p;   p += (size_t)N8 * 4;
    int* bsum   = (int*)p;   p += (size_t)nb * 4;
    int* ptr8   = (int*)p;   p += (size_t)(N8 + 1) * 4;
    int* rank   = (int*)p;   p += (size_t)E * 4;
    int* srcs   = (int*)p;   p += (size_t)Et * 4;

    hipLaunchKernelGGL(k_init_cnt, dim3(1024), dim3(256), 0, stream, cnt, N, N8);

    const int nH  = (E4 + 255) / 256;        // 3125 hist blocks
    const int nN1 = (N * NH + 255) / 256;    // 3125 node1 blocks
    hipLaunchKernelGGL(k_hist_node1, dim3(nH + nN1), dim3(256), 0, stream,
                       ei, E4, cnt, rank, x, W1, as1, ad1, h1b, a_s1, a_d1, N, nH);

    hipLaunchKernelGGL(k_scan_block8, dim3(nb), dim3(256), 0, stream, cnt, ptrtmp, bsum, N);
    hipLaunchKernelGGL(k_scan_bsums, dim3(1), dim3(512), 0, stream, bsum, nb);
    hipLaunchKernelGGL(k_scan_finalize, dim3((N8 + 256) / 256), dim3(256), 0, stream,
                       ptrtmp, bsum, ptr8, N8, Et);

    const int nSc   = (E + SC_EDGES - 1) / SC_EDGES;   // 1563
    const int nLoop = (N + 255) / 256;                 // 391
    hipLaunchKernelGGL(k_scatter, dim3(nSc + nLoop), dim3(256), 0, stream,
                       ei, E4, rank, ptr8, srcs, N, nSc);

    hipLaunchKernelGGL(k_gat1, dim3((N + 3) / 4), dim3(256), 0, stream,
                       ptr8, srcs, a_s1, a_d1, h1b, b1, W2, as2, ad2, h2, a_s2, a_d2, N);

    hipLaunchKernelGGL(k_gat2, dim3((N * 16 + 255) / 256), dim3(256), 0, stream,
                       ptr8, srcs, a_s2, a_d2, h2, b2, out, N);
}

// Round 13
// 218.268 us; speedup vs baseline: 1.7248x; 1.7248x over previous
//
#include <hip/hip_runtime.h>
#include <math.h>

#define F_IN 32
#define NH 8
#define C1 8
#define D1 64
#define NEG 0.2f
#define LOG2E 1.44269504088896f
#define SHBIAS (-20.0f * LOG2E)   // fixed softmax shift (shift-invariant, avoids overflow)

typedef int iv4 __attribute__((ext_vector_type(4)));
typedef unsigned short ushort_t;

__device__ __forceinline__ ushort_t f2bf(float f) {   // RNE float->bf16
    unsigned int b = __float_as_uint(f);
    return (ushort_t)((b + 0x7FFF + ((b >> 16) & 1)) >> 16);
}
__device__ __forceinline__ float bf2f(ushort_t u) {
    return __uint_as_float(((unsigned int)u) << 16);
}

// =============== CSR build: two-level counting sort, ZERO global atomics ===============
// (R10-R12: ANY per-edge global atomic caps at ~22G/s = 143us on the memory-side
//  coherence point, regardless of layout. So: LDS atomics only.)
// bucket = dst >> 8 (256 nodes/bucket, nbk = ceil(N/256) buckets)
// Pass A: per-block LDS bucket hist -> blkcnt[bucket*GA + block]   (|| node1)
// Pass B: exclusive scan of flat blkcnt -> excl[] = all write bases
// Pass C: partition edges into bucket windows, packed (src<<8)|(dst&255)
// Pass D: per-bucket LDS node-hist + scan -> ptr, srcs (self-loop = slot 0)

// ---- node1: h = x@W1 (stored bf16), attention logits a_s/a_d (f32) ----
__device__ __forceinline__ void node1_body(const float* __restrict__ x, const float* __restrict__ W1,
                                           const float* __restrict__ as1, const float* __restrict__ ad1,
                                           ushort_t* __restrict__ h1b, float* __restrict__ a_s,
                                           float* __restrict__ a_d, int N, int b) {
    __shared__ float sW[F_IN * D1];
    __shared__ float sA[2 * D1];
    for (int i = threadIdx.x; i < F_IN * D1; i += blockDim.x) sW[i] = W1[i];
    if (threadIdx.x < 2 * D1)
        sA[threadIdx.x] = (threadIdx.x < D1) ? as1[threadIdx.x] : ad1[threadIdx.x - D1];
    __syncthreads();
    int t = b * blockDim.x + threadIdx.x;
    int n = t >> 3, h = t & 7;
    if (n >= N) return;
    float xr[F_IN];
    const float4* xv = (const float4*)(x + n * F_IN);
#pragma unroll
    for (int k = 0; k < F_IN / 4; ++k) {
        float4 v = xv[k];
        xr[4 * k] = v.x; xr[4 * k + 1] = v.y; xr[4 * k + 2] = v.z; xr[4 * k + 3] = v.w;
    }
    float acc[C1];
#pragma unroll
    for (int c = 0; c < C1; ++c) acc[c] = 0.0f;
#pragma unroll
    for (int k = 0; k < F_IN; ++k) {
        float xk = xr[k];
#pragma unroll
        for (int c = 0; c < C1; ++c) acc[c] = fmaf(xk, sW[k * D1 + h * C1 + c], acc[c]);
    }
    float s_ = 0.0f, d_ = 0.0f;
    unsigned int w[4];
#pragma unroll
    for (int c = 0; c < C1; ++c) {
        s_ = fmaf(acc[c], sA[h * C1 + c], s_);
        d_ = fmaf(acc[c], sA[D1 + h * C1 + c], d_);
    }
#pragma unroll
    for (int k = 0; k < 4; ++k)
        w[k] = (unsigned int)f2bf(acc[2 * k]) | ((unsigned int)f2bf(acc[2 * k + 1]) << 16);
    iv4 wv = {(int)w[0], (int)w[1], (int)w[2], (int)w[3]};
    *(iv4*)(h1b + (size_t)n * D1 + h * C1) = wv;
    a_s[n * NH + h] = s_;
    a_d[n * NH + h] = d_;
}

// ---- Pass A (|| node1): per-block bucket histogram, 8192 edges/block ----
__global__ void __launch_bounds__(256)
k_bhist_node1(const int* __restrict__ ei, int E4, int GA, int nbk,
              int* __restrict__ blkcnt,
              const float* __restrict__ x, const float* __restrict__ W1,
              const float* __restrict__ as1, const float* __restrict__ ad1,
              ushort_t* __restrict__ h1b, float* __restrict__ a_s, float* __restrict__ a_d,
              int N) {
    int g = blockIdx.x;
    if (g >= GA) { node1_body(x, W1, as1, ad1, h1b, a_s, a_d, N, g - GA); return; }
    __shared__ int hist[512];
    for (int i = threadIdx.x; i < nbk; i += 256) hist[i] = 0;
    __syncthreads();
    const iv4* d4 = (const iv4*)ei + E4;
    int base = g * 2048 + threadIdx.x;
#pragma unroll
    for (int k = 0; k < 8; ++k) {
        int idx = base + k * 256;
        if (idx < E4) {
            iv4 d = __builtin_nontemporal_load(d4 + idx);
            atomicAdd(&hist[d.x >> 8], 1);
            atomicAdd(&hist[d.y >> 8], 1);
            atomicAdd(&hist[d.z >> 8], 1);
            atomicAdd(&hist[d.w >> 8], 1);
        }
    }
    __syncthreads();
    for (int i = threadIdx.x; i < nbk; i += 256) blkcnt[(size_t)i * GA + g] = hist[i];
}

// ---- Pass B: two-level exclusive scan over flat blkcnt (F = nbk*GA) ----
__global__ void k_scan_block(const int* __restrict__ in, int* __restrict__ tmp,
                             int* __restrict__ bsum, int F) {
    __shared__ int s[256];
    int i = blockIdx.x * 256 + threadIdx.x;
    int v = (i < F) ? in[i] : 0;
    s[threadIdx.x] = v;
    __syncthreads();
#pragma unroll
    for (int off = 1; off < 256; off <<= 1) {
        int t = (threadIdx.x >= off) ? s[threadIdx.x - off] : 0;
        __syncthreads();
        s[threadIdx.x] += t;
        __syncthreads();
    }
    tmp[i] = s[threadIdx.x] - v;
    if (threadIdx.x == 255) bsum[blockIdx.x] = s[255];
}

__global__ void k_scan_bsums1024(int* __restrict__ bsum, int nb) {
    __shared__ int s[1024];
    int t = threadIdx.x;
    s[t] = (t < nb) ? bsum[t] : 0;
    __syncthreads();
#pragma unroll
    for (int off = 1; off < 1024; off <<= 1) {
        int v = (t >= off) ? s[t - off] : 0;
        __syncthreads();
        s[t] += v;
        __syncthreads();
    }
    if (t < nb) bsum[t] = (t == 0) ? 0 : s[t - 1];
}

__global__ void k_scan_fin(const int* __restrict__ tmp, const int* __restrict__ bsum,
                           int* __restrict__ excl, int F, int E) {
    int i = blockIdx.x * blockDim.x + threadIdx.x;
    if (i > F) return;
    excl[i] = (i < F) ? (tmp[i] + bsum[i >> 8]) : E;
}

// ---- Pass C: partition edges into bucket windows (LDS cursors) ----
__global__ void __launch_bounds__(256)
k_part(const int* __restrict__ ei, int E4, int GA, int nbk,
       const int* __restrict__ excl, int* __restrict__ partbuf) {
    __shared__ int cur[512];
    int g = blockIdx.x;
    for (int i = threadIdx.x; i < nbk; i += 256) cur[i] = excl[(size_t)i * GA + g];
    __syncthreads();
    const iv4* s4 = (const iv4*)ei;
    const iv4* d4 = s4 + E4;
    int base = g * 2048 + threadIdx.x;
#pragma unroll
    for (int k = 0; k < 8; ++k) {
        int idx = base + k * 256;
        if (idx < E4) {
            iv4 d = __builtin_nontemporal_load(d4 + idx);
            iv4 s = __builtin_nontemporal_load(s4 + idx);
            int dd[4] = {d.x, d.y, d.z, d.w};
            int ss[4] = {s.x, s.y, s.z, s.w};
#pragma unroll
            for (int u = 0; u < 4; ++u) {
                int pos = atomicAdd(&cur[dd[u] >> 8], 1);
                partbuf[pos] = (ss[u] << 8) | (dd[u] & 255);
            }
        }
    }
}

// ---- Pass D: per-bucket CSR (LDS node hist + scan; self-loop = slot 0) ----
__global__ void __launch_bounds__(256)
k_csr(const int* __restrict__ excl, const int* __restrict__ partbuf,
      int* __restrict__ ptr, int* __restrict__ srcs, int N, int GA, int nbk, int Et) {
    __shared__ int lcnt[256];
    __shared__ int lsc[256];
    int b = blockIdx.x;
    int tid = threadIdx.x;
    int pStart = excl[(size_t)b * GA];
    int pEnd   = excl[(size_t)(b + 1) * GA];   // b==nbk-1 -> excl[F] = E
    int node = (b << 8) + tid;
    int exists = (node < N) ? 1 : 0;
    lcnt[tid] = exists;                        // slot 0 reserved for self-loop
    __syncthreads();
    for (int i = pStart + tid; i < pEnd; i += 256)
        atomicAdd(&lcnt[partbuf[i] & 255], 1);
    __syncthreads();
    int v = lcnt[tid];
    lsc[tid] = v;
    __syncthreads();
#pragma unroll
    for (int off = 1; off < 256; off <<= 1) {
        int t = (tid >= off) ? lsc[tid - off] : 0;
        __syncthreads();
        lsc[tid] += t;
        __syncthreads();
    }
    int exclv = lsc[tid] - v;
    int finalBase = pStart + (b << 8);         // + self-loops of earlier buckets
    if (exists) {
        int p = finalBase + exclv;
        ptr[node] = p;
        srcs[p] = node;                        // self-loop at rank 0
    }
    if (b == nbk - 1 && tid == 0) ptr[N] = Et;
    __syncthreads();
    lcnt[tid] = exclv + exists;                // cursor: next free slot after self-loop
    __syncthreads();
    for (int i = pStart + tid; i < pEnd; i += 256) {
        int pv = partbuf[i];
        int r = atomicAdd(&lcnt[pv & 255], 1);
        srcs[finalBase + r] = pv >> 8;
    }
}

// ---------------- layer 1: wave per node, transposed logit phase ----------------

__device__ __forceinline__ float lrelu(float e) { return e > 0.0f ? e : NEG * e; }

__global__ void __launch_bounds__(256)
k_gat1(const int* __restrict__ ptr, const int* __restrict__ srcs,
       const float* __restrict__ a_s, const float* __restrict__ a_d,
       const ushort_t* __restrict__ h1b,
       const float* __restrict__ b1, const float* __restrict__ W2,
       const float* __restrict__ as2, const float* __restrict__ ad2,
       float* __restrict__ h2, float* __restrict__ a_s2o, float* __restrict__ a_d2o,
       int N) {
    int n = (blockIdx.x * blockDim.x + threadIdx.x) >> 6;
    if (n >= N) return;
    int l = threadIdx.x & 63;
    int j = l >> 3;          // edge slot (logit phase)
    int h = l & 7;           // head (logit phase)
    int start = ptr[n], end = ptr[n + 1];
    float ad = a_d[n * NH + h];
    const ushort_t* hb = h1b + l;    // lane-fixed offset into bf16 h rows
    float den = 0.0f, acc = 0.0f;
    for (int base = start; base < end; base += 8) {
        int idxl = base + j;
        bool valid = idxl < end;
        if (!valid) idxl = end - 1;
        int s = srcs[idxl];                         // 8 consecutive ints, group-shared
        float as = a_s[(s << 3) + h];               // 8x32B contiguous segments
        float ex = exp2f(fmaf(lrelu(as + ad), LOG2E, SHBIAS));
        if (!valid) ex = 0.0f;
        den += ex;                                   // per-lane (j,h) partial
        int s0 = __builtin_amdgcn_readlane(s, 0),  s1 = __builtin_amdgcn_readlane(s, 8);
        int s2 = __builtin_amdgcn_readlane(s, 16), s3 = __builtin_amdgcn_readlane(s, 24);
        int s4 = __builtin_amdgcn_readlane(s, 32), s5 = __builtin_amdgcn_readlane(s, 40);
        int s6 = __builtin_amdgcn_readlane(s, 48), s7 = __builtin_amdgcn_readlane(s, 56);
        float g0 = bf2f(hb[s0 << 6]), g1 = bf2f(hb[s1 << 6]);
        float g2 = bf2f(hb[s2 << 6]), g3 = bf2f(hb[s3 << 6]);
        float g4 = bf2f(hb[s4 << 6]), g5 = bf2f(hb[s5 << 6]);
        float g6 = bf2f(hb[s6 << 6]), g7 = bf2f(hb[s7 << 6]);
        int bl = l >> 3;
        float e0 = __shfl(ex, 0 + bl, 64),  e1 = __shfl(ex, 8 + bl, 64);
        float e2 = __shfl(ex, 16 + bl, 64), e3 = __shfl(ex, 24 + bl, 64);
        float e4 = __shfl(ex, 32 + bl, 64), e5 = __shfl(ex, 40 + bl, 64);
        float e6 = __shfl(ex, 48 + bl, 64), e7 = __shfl(ex, 56 + bl, 64);
        acc = fmaf(e0, g0, acc); acc = fmaf(e1, g1, acc);
        acc = fmaf(e2, g2, acc); acc = fmaf(e3, g3, acc);
        acc = fmaf(e4, g4, acc); acc = fmaf(e5, g5, acc);
        acc = fmaf(e6, g6, acc); acc = fmaf(e7, g7, acc);
    }
    den += __shfl_xor(den, 8, 64);
    den += __shfl_xor(den, 16, 64);
    den += __shfl_xor(den, 32, 64);
    den = __shfl(den, l >> 3, 64);   // re-layout: lane l gets den[h = l>>3]
    float v = acc / den + b1[l];
    v = v > 0.0f ? v : expm1f(v);    // ELU
    float r0 = v * W2[l * 2 + 0];
    float r1 = v * W2[l * 2 + 1];
#pragma unroll
    for (int off = 32; off; off >>= 1) {
        r0 += __shfl_xor(r0, off, 64);
        r1 += __shfl_xor(r1, off, 64);
    }
    if (l == 0) {
        h2[n * 2 + 0] = r0;
        h2[n * 2 + 1] = r1;
        a_s2o[n] = r0 * as2[0] + r1 * as2[1];
        a_d2o[n] = r0 * ad2[0] + r1 * ad2[1];
    }
}

// ---------------- layer 2: 16 lanes per node (avg degree ~33) ----------------

__global__ void k_gat2(const int* __restrict__ ptr, const int* __restrict__ srcs,
                       const float* __restrict__ a_s2, const float* __restrict__ a_d2,
                       const float* __restrict__ h2, const float* __restrict__ b2,
                       float* __restrict__ out, int N) {
    int t = blockIdx.x * blockDim.x + threadIdx.x;
    int n = t >> 4;
    if (n >= N) return;
    int l = threadIdx.x & 15;
    int start = ptr[n], end = ptr[n + 1];
    float ad = a_d2[n];
    float den = 0.0f, a0 = 0.0f, a1 = 0.0f;
    for (int idx = start + l; idx < end; idx += 16) {
        int s = srcs[idx];
        float ex = exp2f(fmaf(lrelu(a_s2[s] + ad), LOG2E, SHBIAS));
        float2 hv = *(const float2*)(h2 + s * 2);
        den += ex;
        a0 = fmaf(ex, hv.x, a0);
        a1 = fmaf(ex, hv.y, a1);
    }
#pragma unroll
    for (int off = 8; off; off >>= 1) {
        den += __shfl_xor(den, off, 16);
        a0  += __shfl_xor(a0, off, 16);
        a1  += __shfl_xor(a1, off, 16);
    }
    if (l == 0) {
        float inv = 1.0f / den;
        float o0 = a0 * inv + b2[0];
        float o1 = a1 * inv + b2[1];
        float mx = fmaxf(o0, o1);
        float lse = mx + logf(__expf(o0 - mx) + __expf(o1 - mx));
        out[n * 2 + 0] = o0 - lse;
        out[n * 2 + 1] = o1 - lse;
    }
}

extern "C" void kernel_launch(void* const* d_in, const int* in_sizes, int n_in,
                              void* d_out, int out_size, void* d_ws, size_t ws_size,
                              hipStream_t stream) {
    const float* x   = (const float*)d_in[0];
    const int*   ei  = (const int*)d_in[1];
    const float* W1  = (const float*)d_in[2];
    const float* as1 = (const float*)d_in[3];
    const float* ad1 = (const float*)d_in[4];
    const float* b1  = (const float*)d_in[5];
    const float* W2  = (const float*)d_in[6];
    const float* as2 = (const float*)d_in[7];
    const float* ad2 = (const float*)d_in[8];
    const float* b2  = (const float*)d_in[9];
    float* out = (float*)d_out;

    const int N  = in_sizes[0] / F_IN;   // 100000
    const int E  = in_sizes[1] / 2;      // 3200000
    const int E4 = E / 4;                // 800000
    const int Et = E + N;
    const int nbk = (N + 255) >> 8;      // 391 buckets
    const int GA  = (E4 + 2047) >> 11;   // 391 edge-chunk blocks (8192 edges each)
    const int F   = nbk * GA;            // 152881 flat scan size
    const int nbScan = (F + 255) >> 8;   // 598 (<=1024)

    char* p = (char*)d_ws;
    ushort_t* h1b = (ushort_t*)p; p += (size_t)N * D1 * 2;   // bf16 h1
    float* a_s1 = (float*)p; p += (size_t)N * NH * 4;
    float* a_d1 = (float*)p; p += (size_t)N * NH * 4;
    float* h2   = (float*)p; p += (size_t)N * 2 * 4;
    float* a_s2 = (float*)p; p += (size_t)N * 4;
    float* a_d2 = (float*)p; p += (size_t)N * 4;
    int* blkcnt = (int*)p;   p += (size_t)F * 4;
    int* tmp    = (int*)p;   p += (size_t)nbScan * 256 * 4;
    int* bsum   = (int*)p;   p += (size_t)nbScan * 4;
    int* excl   = (int*)p;   p += (size_t)(F + 1) * 4;
    int* partbuf= (int*)p;   p += (size_t)E * 4;
    int* ptr    = (int*)p;   p += (size_t)(N + 1) * 4;
    int* srcs   = (int*)p;   p += (size_t)Et * 4;

    const int nN1 = (N * NH + 255) / 256;    // 3125 node1 blocks

    hipLaunchKernelGGL(k_bhist_node1, dim3(GA + nN1), dim3(256), 0, stream,
                       ei, E4, GA, nbk, blkcnt, x, W1, as1, ad1, h1b, a_s1, a_d1, N);

    hipLaunchKernelGGL(k_scan_block, dim3(nbScan), dim3(256), 0, stream, blkcnt, tmp, bsum, F);
    hipLaunchKernelGGL(k_scan_bsums1024, dim3(1), dim3(1024), 0, stream, bsum, nbScan);
    hipLaunchKernelGGL(k_scan_fin, dim3((F + 256) / 256), dim3(256), 0, stream,
                       tmp, bsum, excl, F, E);

    hipLaunchKernelGGL(k_part, dim3(GA), dim3(256), 0, stream, ei, E4, GA, nbk, excl, partbuf);

    hipLaunchKernelGGL(k_csr, dim3(nbk), dim3(256), 0, stream,
                       excl, partbuf, ptr, srcs, N, GA, nbk, Et);

    hipLaunchKernelGGL(k_gat1, dim3((N + 3) / 4), dim3(256), 0, stream,
                       ptr, srcs, a_s1, a_d1, h1b, b1, W2, as2, ad2, h2, a_s2, a_d2, N);

    hipLaunchKernelGGL(k_gat2, dim3((N * 16 + 255) / 256), dim3(256), 0, stream,
                       ptr, srcs, a_s2, a_d2, h2, b2, out, N);
}

// Round 14
// 213.532 us; speedup vs baseline: 1.7630x; 1.0222x over previous
//
#include <hip/hip_runtime.h>
#include <math.h>

#define F_IN 32
#define NH 8
#define C1 8
#define D1 64
#define NEG 0.2f
#define LOG2E 1.44269504088896f
#define SHBIAS (-20.0f * LOG2E)   // fixed softmax shift (shift-invariant, avoids overflow)

typedef int iv4 __attribute__((ext_vector_type(4)));
typedef unsigned short ushort_t;

__device__ __forceinline__ ushort_t f2bf(float f) {   // RNE float->bf16
    unsigned int b = __float_as_uint(f);
    return (ushort_t)((b + 0x7FFF + ((b >> 16) & 1)) >> 16);
}

// =============== CSR build: two-level counting sort, ZERO global atomics ===============
// (R10-R12: ANY per-edge global atomic caps at ~22G/s = 143us on the memory-side
//  coherence point, regardless of layout. So: LDS atomics only.)

// ---- node1: h = x@W1 (stored bf16), attention logits a_s/a_d (f32) ----
__device__ __forceinline__ void node1_body(const float* __restrict__ x, const float* __restrict__ W1,
                                           const float* __restrict__ as1, const float* __restrict__ ad1,
                                           ushort_t* __restrict__ h1b, float* __restrict__ a_s,
                                           float* __restrict__ a_d, int N, int b) {
    __shared__ float sW[F_IN * D1];
    __shared__ float sA[2 * D1];
    for (int i = threadIdx.x; i < F_IN * D1; i += blockDim.x) sW[i] = W1[i];
    if (threadIdx.x < 2 * D1)
        sA[threadIdx.x] = (threadIdx.x < D1) ? as1[threadIdx.x] : ad1[threadIdx.x - D1];
    __syncthreads();
    int t = b * blockDim.x + threadIdx.x;
    int n = t >> 3, h = t & 7;
    if (n >= N) return;
    float xr[F_IN];
    const float4* xv = (const float4*)(x + n * F_IN);
#pragma unroll
    for (int k = 0; k < F_IN / 4; ++k) {
        float4 v = xv[k];
        xr[4 * k] = v.x; xr[4 * k + 1] = v.y; xr[4 * k + 2] = v.z; xr[4 * k + 3] = v.w;
    }
    float acc[C1];
#pragma unroll
    for (int c = 0; c < C1; ++c) acc[c] = 0.0f;
#pragma unroll
    for (int k = 0; k < F_IN; ++k) {
        float xk = xr[k];
#pragma unroll
        for (int c = 0; c < C1; ++c) acc[c] = fmaf(xk, sW[k * D1 + h * C1 + c], acc[c]);
    }
    float s_ = 0.0f, d_ = 0.0f;
    unsigned int w[4];
#pragma unroll
    for (int c = 0; c < C1; ++c) {
        s_ = fmaf(acc[c], sA[h * C1 + c], s_);
        d_ = fmaf(acc[c], sA[D1 + h * C1 + c], d_);
    }
#pragma unroll
    for (int k = 0; k < 4; ++k)
        w[k] = (unsigned int)f2bf(acc[2 * k]) | ((unsigned int)f2bf(acc[2 * k + 1]) << 16);
    iv4 wv = {(int)w[0], (int)w[1], (int)w[2], (int)w[3]};
    *(iv4*)(h1b + (size_t)n * D1 + h * C1) = wv;
    a_s[n * NH + h] = s_;
    a_d[n * NH + h] = d_;
}

// ---- Pass A (|| node1): per-block bucket histogram, 8192 edges/block ----
__global__ void __launch_bounds__(256)
k_bhist_node1(const int* __restrict__ ei, int E4, int GA, int nbk,
              int* __restrict__ blkcnt,
              const float* __restrict__ x, const float* __restrict__ W1,
              const float* __restrict__ as1, const float* __restrict__ ad1,
              ushort_t* __restrict__ h1b, float* __restrict__ a_s, float* __restrict__ a_d,
              int N) {
    int g = blockIdx.x;
    if (g >= GA) { node1_body(x, W1, as1, ad1, h1b, a_s, a_d, N, g - GA); return; }
    __shared__ int hist[512];
    for (int i = threadIdx.x; i < nbk; i += 256) hist[i] = 0;
    __syncthreads();
    const iv4* d4 = (const iv4*)ei + E4;
    int base = g * 2048 + threadIdx.x;
#pragma unroll
    for (int k = 0; k < 8; ++k) {
        int idx = base + k * 256;
        if (idx < E4) {
            iv4 d = __builtin_nontemporal_load(d4 + idx);
            atomicAdd(&hist[d.x >> 8], 1);
            atomicAdd(&hist[d.y >> 8], 1);
            atomicAdd(&hist[d.z >> 8], 1);
            atomicAdd(&hist[d.w >> 8], 1);
        }
    }
    __syncthreads();
    for (int i = threadIdx.x; i < nbk; i += 256) blkcnt[(size_t)i * GA + g] = hist[i];
}

// ---- Pass B: two-level exclusive scan over flat blkcnt (F = nbk*GA) ----
__global__ void k_scan_block(const int* __restrict__ in, int* __restrict__ tmp,
                             int* __restrict__ bsum, int F) {
    __shared__ int s[256];
    int i = blockIdx.x * 256 + threadIdx.x;
    int v = (i < F) ? in[i] : 0;
    s[threadIdx.x] = v;
    __syncthreads();
#pragma unroll
    for (int off = 1; off < 256; off <<= 1) {
        int t = (threadIdx.x >= off) ? s[threadIdx.x - off] : 0;
        __syncthreads();
        s[threadIdx.x] += t;
        __syncthreads();
    }
    tmp[i] = s[threadIdx.x] - v;
    if (threadIdx.x == 255) bsum[blockIdx.x] = s[255];
}

__global__ void k_scan_bsums1024(int* __restrict__ bsum, int nb) {
    __shared__ int s[1024];
    int t = threadIdx.x;
    s[t] = (t < nb) ? bsum[t] : 0;
    __syncthreads();
#pragma unroll
    for (int off = 1; off < 1024; off <<= 1) {
        int v = (t >= off) ? s[t - off] : 0;
        __syncthreads();
        s[t] += v;
        __syncthreads();
    }
    if (t < nb) bsum[t] = (t == 0) ? 0 : s[t - 1];
}

__global__ void k_scan_fin(const int* __restrict__ tmp, const int* __restrict__ bsum,
                           int* __restrict__ excl, int F, int E) {
    int i = blockIdx.x * blockDim.x + threadIdx.x;
    if (i > F) return;
    excl[i] = (i < F) ? (tmp[i] + bsum[i >> 8]) : E;
}

// ---- Pass C: partition edges into bucket windows (LDS cursors) ----
__global__ void __launch_bounds__(256)
k_part(const int* __restrict__ ei, int E4, int GA, int nbk,
       const int* __restrict__ excl, int* __restrict__ partbuf) {
    __shared__ int cur[512];
    int g = blockIdx.x;
    for (int i = threadIdx.x; i < nbk; i += 256) cur[i] = excl[(size_t)i * GA + g];
    __syncthreads();
    const iv4* s4 = (const iv4*)ei;
    const iv4* d4 = s4 + E4;
    int base = g * 2048 + threadIdx.x;
#pragma unroll
    for (int k = 0; k < 8; ++k) {
        int idx = base + k * 256;
        if (idx < E4) {
            iv4 d = __builtin_nontemporal_load(d4 + idx);
            iv4 s = __builtin_nontemporal_load(s4 + idx);
            int dd[4] = {d.x, d.y, d.z, d.w};
            int ss[4] = {s.x, s.y, s.z, s.w};
#pragma unroll
            for (int u = 0; u < 4; ++u) {
                int pos = atomicAdd(&cur[dd[u] >> 8], 1);
                partbuf[pos] = (ss[u] << 8) | (dd[u] & 255);
            }
        }
    }
}

// ---- Pass D: per-bucket CSR (LDS node hist + scan; self-loop = slot 0) ----
__global__ void __launch_bounds__(256)
k_csr(const int* __restrict__ excl, const int* __restrict__ partbuf,
      int* __restrict__ ptr, int* __restrict__ srcs, int N, int GA, int nbk, int Et) {
    __shared__ int lcnt[256];
    __shared__ int lsc[256];
    int b = blockIdx.x;
    int tid = threadIdx.x;
    int pStart = excl[(size_t)b * GA];
    int pEnd   = excl[(size_t)(b + 1) * GA];   // b==nbk-1 -> excl[F] = E
    int node = (b << 8) + tid;
    int exists = (node < N) ? 1 : 0;
    lcnt[tid] = exists;                        // slot 0 reserved for self-loop
    __syncthreads();
    for (int i = pStart + tid; i < pEnd; i += 256)
        atomicAdd(&lcnt[partbuf[i] & 255], 1);
    __syncthreads();
    int v = lcnt[tid];
    lsc[tid] = v;
    __syncthreads();
#pragma unroll
    for (int off = 1; off < 256; off <<= 1) {
        int t = (tid >= off) ? lsc[tid - off] : 0;
        __syncthreads();
        lsc[tid] += t;
        __syncthreads();
    }
    int exclv = lsc[tid] - v;
    int finalBase = pStart + (b << 8);         // + self-loops of earlier buckets
    if (exists) {
        int p = finalBase + exclv;
        ptr[node] = p;
        srcs[p] = node;                        // self-loop at rank 0
    }
    if (b == nbk - 1 && tid == 0) ptr[N] = Et;
    __syncthreads();
    lcnt[tid] = exclv + exists;                // cursor: next free slot after self-loop
    __syncthreads();
    for (int i = pStart + tid; i < pEnd; i += 256) {
        int pv = partbuf[i];
        int r = atomicAdd(&lcnt[pv & 255], 1);
        srcs[finalBase + r] = pv >> 8;
    }
}

// ---------------- layer 1: wave per node, vectorized row gather ----------------
// Lane (j = l>>3, h = l&7): logit for (edge j, head h), AND one dwordx4 load
// grabs head h's 8 channels of row s_j (row = 128B = 8 lanes x 16B). ex and the
// gathered channels land in the SAME lane -> zero per-edge shuffles; per-lane
// acc[8] over the j-subset, 24-shfl reduction once per node in the epilogue.

__device__ __forceinline__ float lrelu(float e) { return e > 0.0f ? e : NEG * e; }

__global__ void __launch_bounds__(256)
k_gat1(const int* __restrict__ ptr, const int* __restrict__ srcs,
       const float* __restrict__ a_s, const float* __restrict__ a_d,
       const ushort_t* __restrict__ h1b,
       const float* __restrict__ b1, const float* __restrict__ W2,
       const float* __restrict__ as2, const float* __restrict__ ad2,
       float4* __restrict__ p2, int N) {
    __shared__ float sB1[D1];
    __shared__ float sW2[D1 * 2];
    __shared__ float sA2[4];
    if (threadIdx.x < D1) sB1[threadIdx.x] = b1[threadIdx.x];
    else if (threadIdx.x < D1 * 3) sW2[threadIdx.x - D1] = W2[threadIdx.x - D1];
    else if (threadIdx.x < D1 * 3 + 2) sA2[threadIdx.x - D1 * 3] = as2[threadIdx.x - D1 * 3];
    else if (threadIdx.x < D1 * 3 + 4) sA2[threadIdx.x - D1 * 3] = ad2[threadIdx.x - D1 * 3 - 2];
    __syncthreads();
    int n = (blockIdx.x * blockDim.x + threadIdx.x) >> 6;
    if (n >= N) return;
    int l = threadIdx.x & 63;
    int j = l >> 3;          // edge slot
    int h = l & 7;           // head
    int start = ptr[n], end = ptr[n + 1];
    float ad = a_d[n * NH + h];
    float den = 0.0f;
    float acc[8];
#pragma unroll
    for (int c = 0; c < 8; ++c) acc[c] = 0.0f;
    for (int base = start; base < end; base += 8) {
        int idxl = base + j;
        bool valid = idxl < end;
        if (!valid) idxl = end - 1;
        int s = srcs[idxl];
        float as = a_s[(s << 3) + h];
        float ex = exp2f(fmaf(lrelu(as + ad), LOG2E, SHBIAS));
        if (!valid) ex = 0.0f;
        den += ex;
        // ONE dwordx4: head h's 8 bf16 channels of row s (wave covers 8 rows)
        iv4 hv = *(const iv4*)(h1b + ((size_t)s << 6) + (h << 3));
        int dw[4] = {hv.x, hv.y, hv.z, hv.w};
#pragma unroll
        for (int k = 0; k < 4; ++k) {
            float lo = __uint_as_float(((unsigned int)dw[k]) << 16);
            float hi = __uint_as_float(((unsigned int)dw[k]) & 0xffff0000u);
            acc[2 * k]     = fmaf(ex, lo, acc[2 * k]);
            acc[2 * k + 1] = fmaf(ex, hi, acc[2 * k + 1]);
        }
    }
    // reduce over j (lane bits 3..5)
    den += __shfl_xor(den, 8, 64);
    den += __shfl_xor(den, 16, 64);
    den += __shfl_xor(den, 32, 64);
#pragma unroll
    for (int c = 0; c < 8; ++c) {
        acc[c] += __shfl_xor(acc[c], 8, 64);
        acc[c] += __shfl_xor(acc[c], 16, 64);
        acc[c] += __shfl_xor(acc[c], 32, 64);
    }
    float inv = 1.0f / den;
    float r0 = 0.0f, r1 = 0.0f;
#pragma unroll
    for (int c = 0; c < 8; ++c) {
        int col = (h << 3) + c;
        float v = fmaf(acc[c], inv, sB1[col]);
        v = v > 0.0f ? v : expm1f(v);    // ELU
        r0 = fmaf(v, sW2[col * 2 + 0], r0);
        r1 = fmaf(v, sW2[col * 2 + 1], r1);
    }
    // sum over h (lane bits 0..2); every j-group redundantly holds the total
    r0 += __shfl_xor(r0, 1, 64); r0 += __shfl_xor(r0, 2, 64); r0 += __shfl_xor(r0, 4, 64);
    r1 += __shfl_xor(r1, 1, 64); r1 += __shfl_xor(r1, 2, 64); r1 += __shfl_xor(r1, 4, 64);
    if (l == 0) {
        // packed node record for layer 2: (a_s2, a_d2, h2_0, h2_1)
        p2[n] = make_float4(r0 * sA2[0] + r1 * sA2[1],
                            r0 * sA2[2] + r1 * sA2[3], r0, r1);
    }
}

// ---------------- layer 2: 16 lanes per node, single 16B gather ----------------

__global__ void k_gat2(const int* __restrict__ ptr, const int* __restrict__ srcs,
                       const float4* __restrict__ p2, const float* __restrict__ b2,
                       float* __restrict__ out, int N) {
    int t = blockIdx.x * blockDim.x + threadIdx.x;
    int n = t >> 4;
    if (n >= N) return;
    int l = threadIdx.x & 15;
    int start = ptr[n], end = ptr[n + 1];
    float ad = p2[n].y;
    float den = 0.0f, a0 = 0.0f, a1 = 0.0f;
    for (int idx = start + l; idx < end; idx += 16) {
        int s = srcs[idx];
        float4 ps = p2[s];
        float ex = exp2f(fmaf(lrelu(ps.x + ad), LOG2E, SHBIAS));
        den += ex;
        a0 = fmaf(ex, ps.z, a0);
        a1 = fmaf(ex, ps.w, a1);
    }
#pragma unroll
    for (int off = 8; off; off >>= 1) {
        den += __shfl_xor(den, off, 16);
        a0  += __shfl_xor(a0, off, 16);
        a1  += __shfl_xor(a1, off, 16);
    }
    if (l == 0) {
        float inv = 1.0f / den;
        float o0 = a0 * inv + b2[0];
        float o1 = a1 * inv + b2[1];
        float mx = fmaxf(o0, o1);
        float lse = mx + logf(__expf(o0 - mx) + __expf(o1 - mx));
        out[n * 2 + 0] = o0 - lse;
        out[n * 2 + 1] = o1 - lse;
    }
}

extern "C" void kernel_launch(void* const* d_in, const int* in_sizes, int n_in,
                              void* d_out, int out_size, void* d_ws, size_t ws_size,
                              hipStream_t stream) {
    const float* x   = (const float*)d_in[0];
    const int*   ei  = (const int*)d_in[1];
    const float* W1  = (const float*)d_in[2];
    const float* as1 = (const float*)d_in[3];
    const float* ad1 = (const float*)d_in[4];
    const float* b1  = (const float*)d_in[5];
    const float* W2  = (const float*)d_in[6];
    const float* as2 = (const float*)d_in[7];
    const float* ad2 = (const float*)d_in[8];
    const float* b2  = (const float*)d_in[9];
    float* out = (float*)d_out;

    const int N  = in_sizes[0] / F_IN;   // 100000
    const int E  = in_sizes[1] / 2;      // 3200000
    const int E4 = E / 4;                // 800000
    const int Et = E + N;
    const int nbk = (N + 255) >> 8;      // 391 buckets
    const int GA  = (E4 + 2047) >> 11;   // 391 edge-chunk blocks (8192 edges each)
    const int F   = nbk * GA;            // 152881 flat scan size
    const int nbScan = (F + 255) >> 8;   // 598 (<=1024)

    char* p = (char*)d_ws;
    ushort_t* h1b = (ushort_t*)p; p += (size_t)N * D1 * 2;   // bf16 h1 (12.8MB, 16B aligned)
    float4* p2  = (float4*)p; p += (size_t)N * 16;           // packed layer-2 node record
    float* a_s1 = (float*)p; p += (size_t)N * NH * 4;
    float* a_d1 = (float*)p; p += (size_t)N * NH * 4;
    int* blkcnt = (int*)p;   p += (size_t)F * 4;
    int* tmp    = (int*)p;   p += (size_t)nbScan * 256 * 4;
    int* bsum   = (int*)p;   p += (size_t)nbScan * 4;
    int* excl   = (int*)p;   p += (size_t)(F + 1) * 4;
    int* partbuf= (int*)p;   p += (size_t)E * 4;
    int* ptr    = (int*)p;   p += (size_t)(N + 1) * 4;
    int* srcs   = (int*)p;   p += (size_t)Et * 4;

    const int nN1 = (N * NH + 255) / 256;    // 3125 node1 blocks

    hipLaunchKernelGGL(k_bhist_node1, dim3(GA + nN1), dim3(256), 0, stream,
                       ei, E4, GA, nbk, blkcnt, x, W1, as1, ad1, h1b, a_s1, a_d1, N);

    hipLaunchKernelGGL(k_scan_block, dim3(nbScan), dim3(256), 0, stream, blkcnt, tmp, bsum, F);
    hipLaunchKernelGGL(k_scan_bsums1024, dim3(1), dim3(1024), 0, stream, bsum, nbScan);
    hipLaunchKernelGGL(k_scan_fin, dim3((F + 256) / 256), dim3(256), 0, stream,
                       tmp, bsum, excl, F, E);

    hipLaunchKernelGGL(k_part, dim3(GA), dim3(256), 0, stream, ei, E4, GA, nbk, excl, partbuf);

    hipLaunchKernelGGL(k_csr, dim3(nbk), dim3(256), 0, stream,
                       excl, partbuf, ptr, srcs, N, GA, nbk, Et);

    hipLaunchKernelGGL(k_gat1, dim3((N + 3) / 4), dim3(256), 0, stream,
                       ptr, srcs, a_s1, a_d1, h1b, b1, W2, as2, ad2, p2, N);

    hipLaunchKernelGGL(k_gat2, dim3((N * 16 + 255) / 256), dim3(256), 0, stream,
                       ptr, srcs, p2, b2, out, N);
}

// Round 15
// 203.561 us; speedup vs baseline: 1.8494x; 1.0490x over previous
//
#include <hip/hip_runtime.h>
#include <math.h>

#define F_IN 32
#define NH 8
#define C1 8
#define D1 64
#define NEG 0.2f
#define LOG2E 1.44269504088896f
#define SHBIAS (-20.0f * LOG2E)   // fixed softmax shift (shift-invariant, avoids overflow)

typedef int iv4 __attribute__((ext_vector_type(4)));
typedef float fv2 __attribute__((ext_vector_type(2)));
typedef unsigned short ushort_t;

__device__ __forceinline__ ushort_t f2bf(float f) {   // RNE float->bf16
    unsigned int b = __float_as_uint(f);
    return (ushort_t)((b + 0x7FFF + ((b >> 16) & 1)) >> 16);
}

// =============== CSR build: two-level counting sort, ZERO global atomics ===============
// (R10-R12: ANY per-edge global atomic caps at ~22G/s = 143us on the memory-side
//  coherence point, regardless of layout. So: LDS atomics only.)

// ---- node1: h = x@W1 (stored bf16), attention logits a_s/a_d (f32) ----
__device__ __forceinline__ void node1_body(const float* __restrict__ x, const float* __restrict__ W1,
                                           const float* __restrict__ as1, const float* __restrict__ ad1,
                                           ushort_t* __restrict__ h1b, float* __restrict__ a_s,
                                           float* __restrict__ a_d, int N, int b) {
    __shared__ float sW[F_IN * D1];
    __shared__ float sA[2 * D1];
    for (int i = threadIdx.x; i < F_IN * D1; i += blockDim.x) sW[i] = W1[i];
    if (threadIdx.x < 2 * D1)
        sA[threadIdx.x] = (threadIdx.x < D1) ? as1[threadIdx.x] : ad1[threadIdx.x - D1];
    __syncthreads();
    int t = b * blockDim.x + threadIdx.x;
    int n = t >> 3, h = t & 7;
    if (n >= N) return;
    float xr[F_IN];
    const float4* xv = (const float4*)(x + n * F_IN);
#pragma unroll
    for (int k = 0; k < F_IN / 4; ++k) {
        float4 v = xv[k];
        xr[4 * k] = v.x; xr[4 * k + 1] = v.y; xr[4 * k + 2] = v.z; xr[4 * k + 3] = v.w;
    }
    float acc[C1];
#pragma unroll
    for (int c = 0; c < C1; ++c) acc[c] = 0.0f;
#pragma unroll
    for (int k = 0; k < F_IN; ++k) {
        float xk = xr[k];
#pragma unroll
        for (int c = 0; c < C1; ++c) acc[c] = fmaf(xk, sW[k * D1 + h * C1 + c], acc[c]);
    }
    float s_ = 0.0f, d_ = 0.0f;
    unsigned int w[4];
#pragma unroll
    for (int c = 0; c < C1; ++c) {
        s_ = fmaf(acc[c], sA[h * C1 + c], s_);
        d_ = fmaf(acc[c], sA[D1 + h * C1 + c], d_);
    }
#pragma unroll
    for (int k = 0; k < 4; ++k)
        w[k] = (unsigned int)f2bf(acc[2 * k]) | ((unsigned int)f2bf(acc[2 * k + 1]) << 16);
    iv4 wv = {(int)w[0], (int)w[1], (int)w[2], (int)w[3]};
    *(iv4*)(h1b + (size_t)n * D1 + h * C1) = wv;
    a_s[n * NH + h] = s_;
    a_d[n * NH + h] = d_;
}

// ---- Pass A (|| node1): per-block bucket histogram, 8192 edges/block ----
__global__ void __launch_bounds__(256)
k_bhist_node1(const int* __restrict__ ei, int E4, int GA, int nbk,
              int* __restrict__ blkcnt,
              const float* __restrict__ x, const float* __restrict__ W1,
              const float* __restrict__ as1, const float* __restrict__ ad1,
              ushort_t* __restrict__ h1b, float* __restrict__ a_s, float* __restrict__ a_d,
              int N) {
    int g = blockIdx.x;
    if (g >= GA) { node1_body(x, W1, as1, ad1, h1b, a_s, a_d, N, g - GA); return; }
    __shared__ int hist[512];
    for (int i = threadIdx.x; i < nbk; i += 256) hist[i] = 0;
    __syncthreads();
    const iv4* d4 = (const iv4*)ei + E4;
    int base = g * 2048 + threadIdx.x;
#pragma unroll
    for (int k = 0; k < 8; ++k) {
        int idx = base + k * 256;
        if (idx < E4) {
            iv4 d = __builtin_nontemporal_load(d4 + idx);
            atomicAdd(&hist[d.x >> 8], 1);
            atomicAdd(&hist[d.y >> 8], 1);
            atomicAdd(&hist[d.z >> 8], 1);
            atomicAdd(&hist[d.w >> 8], 1);
        }
    }
    __syncthreads();
    for (int i = threadIdx.x; i < nbk; i += 256) blkcnt[(size_t)i * GA + g] = hist[i];
}

// ---- Pass B: two-level exclusive scan over flat blkcnt (F = nbk*GA) ----
__global__ void k_scan_block(const int* __restrict__ in, int* __restrict__ tmp,
                             int* __restrict__ bsum, int F) {
    __shared__ int s[256];
    int i = blockIdx.x * 256 + threadIdx.x;
    int v = (i < F) ? in[i] : 0;
    s[threadIdx.x] = v;
    __syncthreads();
#pragma unroll
    for (int off = 1; off < 256; off <<= 1) {
        int t = (threadIdx.x >= off) ? s[threadIdx.x - off] : 0;
        __syncthreads();
        s[threadIdx.x] += t;
        __syncthreads();
    }
    tmp[i] = s[threadIdx.x] - v;
    if (threadIdx.x == 255) bsum[blockIdx.x] = s[255];
}

__global__ void k_scan_bsums1024(int* __restrict__ bsum, int nb) {
    __shared__ int s[1024];
    int t = threadIdx.x;
    s[t] = (t < nb) ? bsum[t] : 0;
    __syncthreads();
#pragma unroll
    for (int off = 1; off < 1024; off <<= 1) {
        int v = (t >= off) ? s[t - off] : 0;
        __syncthreads();
        s[t] += v;
        __syncthreads();
    }
    if (t < nb) bsum[t] = (t == 0) ? 0 : s[t - 1];
}

__global__ void k_scan_fin(const int* __restrict__ tmp, const int* __restrict__ bsum,
                           int* __restrict__ excl, int F, int E) {
    int i = blockIdx.x * blockDim.x + threadIdx.x;
    if (i > F) return;
    excl[i] = (i < F) ? (tmp[i] + bsum[i >> 8]) : E;
}

// ---- Pass C: partition edges into bucket windows (LDS cursors) ----
__global__ void __launch_bounds__(256)
k_part(const int* __restrict__ ei, int E4, int GA, int nbk,
       const int* __restrict__ excl, int* __restrict__ partbuf) {
    __shared__ int cur[512];
    int g = blockIdx.x;
    for (int i = threadIdx.x; i < nbk; i += 256) cur[i] = excl[(size_t)i * GA + g];
    __syncthreads();
    const iv4* s4 = (const iv4*)ei;
    const iv4* d4 = s4 + E4;
    int base = g * 2048 + threadIdx.x;
#pragma unroll
    for (int k = 0; k < 8; ++k) {
        int idx = base + k * 256;
        if (idx < E4) {
            iv4 d = __builtin_nontemporal_load(d4 + idx);
            iv4 s = __builtin_nontemporal_load(s4 + idx);
            int dd[4] = {d.x, d.y, d.z, d.w};
            int ss[4] = {s.x, s.y, s.z, s.w};
#pragma unroll
            for (int u = 0; u < 4; ++u) {
                int pos = atomicAdd(&cur[dd[u] >> 8], 1);
                partbuf[pos] = (ss[u] << 8) | (dd[u] & 255);
            }
        }
    }
}

// ---- Pass D: per-bucket CSR (LDS node hist + scan; self-loop = slot 0) ----
__global__ void __launch_bounds__(256)
k_csr(const int* __restrict__ excl, const int* __restrict__ partbuf,
      int* __restrict__ ptr, int* __restrict__ srcs, int N, int GA, int nbk, int Et) {
    __shared__ int lcnt[256];
    __shared__ int lsc[256];
    int b = blockIdx.x;
    int tid = threadIdx.x;
    int pStart = excl[(size_t)b * GA];
    int pEnd   = excl[(size_t)(b + 1) * GA];   // b==nbk-1 -> excl[F] = E
    int node = (b << 8) + tid;
    int exists = (node < N) ? 1 : 0;
    lcnt[tid] = exists;                        // slot 0 reserved for self-loop
    __syncthreads();
    for (int i = pStart + tid; i < pEnd; i += 256)
        atomicAdd(&lcnt[partbuf[i] & 255], 1);
    __syncthreads();
    int v = lcnt[tid];
    lsc[tid] = v;
    __syncthreads();
#pragma unroll
    for (int off = 1; off < 256; off <<= 1) {
        int t = (tid >= off) ? lsc[tid - off] : 0;
        __syncthreads();
        lsc[tid] += t;
        __syncthreads();
    }
    int exclv = lsc[tid] - v;
    int finalBase = pStart + (b << 8);         // + self-loops of earlier buckets
    if (exists) {
        int p = finalBase + exclv;
        ptr[node] = p;
        srcs[p] = node;                        // self-loop at rank 0
    }
    if (b == nbk - 1 && tid == 0) ptr[N] = Et;
    __syncthreads();
    lcnt[tid] = exclv + exists;                // cursor: next free slot after self-loop
    __syncthreads();
    for (int i = pStart + tid; i < pEnd; i += 256) {
        int pv = partbuf[i];
        int r = atomicAdd(&lcnt[pv & 255], 1);
        srcs[finalBase + r] = pv >> 8;
    }
}

// ---------------- layer 1: wave per node, vectorized row gather + pk_fma ----------------
// Lane (j = l>>3, h = l&7). Main loop is maskless (base+16<=end), 2 edge-groups
// in flight (4 gathers), float2 accumulators -> v_pk_fma_f32 halves FMA count.

__device__ __forceinline__ float lrelu(float e) { return e > 0.0f ? e : NEG * e; }

__global__ void __launch_bounds__(256)
k_gat1(const int* __restrict__ ptr, const int* __restrict__ srcs,
       const float* __restrict__ a_s, const float* __restrict__ a_d,
       const ushort_t* __restrict__ h1b,
       const float* __restrict__ b1, const float* __restrict__ W2,
       const float* __restrict__ as2, const float* __restrict__ ad2,
       float4* __restrict__ p2, int N) {
    __shared__ float sB1[D1];
    __shared__ float sW2[D1 * 2];
    __shared__ float sA2[4];
    if (threadIdx.x < D1) sB1[threadIdx.x] = b1[threadIdx.x];
    else if (threadIdx.x < D1 * 3) sW2[threadIdx.x - D1] = W2[threadIdx.x - D1];
    else if (threadIdx.x < D1 * 3 + 2) sA2[threadIdx.x - D1 * 3] = as2[threadIdx.x - D1 * 3];
    else if (threadIdx.x < D1 * 3 + 4) sA2[threadIdx.x - D1 * 3] = ad2[threadIdx.x - D1 * 3 - 2];
    __syncthreads();
    int n = (blockIdx.x * blockDim.x + threadIdx.x) >> 6;
    if (n >= N) return;
    int l = threadIdx.x & 63;
    int j = l >> 3;          // edge slot
    int h = l & 7;           // head
    int start = ptr[n], end = ptr[n + 1];
    float ad = a_d[n * NH + h];
    float den = 0.0f;
    fv2 acc2[4];
#pragma unroll
    for (int k = 0; k < 4; ++k) acc2[k] = (fv2){0.0f, 0.0f};
    int base = start;
    // maskless main loop: 16 edges/iter, 2 groups pipelined
    for (; base + 16 <= end; base += 16) {
        int i0 = base + j;
        int s0 = srcs[i0], s1 = srcs[i0 + 8];
        float as0 = a_s[(s0 << 3) + h], as1 = a_s[(s1 << 3) + h];
        iv4 hv0 = *(const iv4*)(h1b + ((size_t)s0 << 6) + (h << 3));
        iv4 hv1 = *(const iv4*)(h1b + ((size_t)s1 << 6) + (h << 3));
        float ex0 = exp2f(fmaf(lrelu(as0 + ad), LOG2E, SHBIAS));
        float ex1 = exp2f(fmaf(lrelu(as1 + ad), LOG2E, SHBIAS));
        den += ex0 + ex1;
        fv2 e0 = {ex0, ex0}, e1 = {ex1, ex1};
        int dw0[4] = {hv0.x, hv0.y, hv0.z, hv0.w};
        int dw1[4] = {hv1.x, hv1.y, hv1.z, hv1.w};
#pragma unroll
        for (int k = 0; k < 4; ++k) {
            fv2 g0 = {__uint_as_float(((unsigned int)dw0[k]) << 16),
                      __uint_as_float(((unsigned int)dw0[k]) & 0xffff0000u)};
            fv2 g1 = {__uint_as_float(((unsigned int)dw1[k]) << 16),
                      __uint_as_float(((unsigned int)dw1[k]) & 0xffff0000u)};
            acc2[k] += e0 * g0;      // v_pk_fma_f32
            acc2[k] += e1 * g1;
        }
    }
    // masked tail (<=15 edges)
    for (; base < end; base += 8) {
        int idxl = base + j;
        bool valid = idxl < end;
        if (!valid) idxl = end - 1;
        int s = srcs[idxl];
        float as = a_s[(s << 3) + h];
        float ex = exp2f(fmaf(lrelu(as + ad), LOG2E, SHBIAS));
        if (!valid) ex = 0.0f;
        den += ex;
        iv4 hv = *(const iv4*)(h1b + ((size_t)s << 6) + (h << 3));
        int dw[4] = {hv.x, hv.y, hv.z, hv.w};
        fv2 ev = {ex, ex};
#pragma unroll
        for (int k = 0; k < 4; ++k) {
            fv2 g = {__uint_as_float(((unsigned int)dw[k]) << 16),
                     __uint_as_float(((unsigned int)dw[k]) & 0xffff0000u)};
            acc2[k] += ev * g;
        }
    }
    // reduce over j (lane bits 3..5)
    den += __shfl_xor(den, 8, 64);
    den += __shfl_xor(den, 16, 64);
    den += __shfl_xor(den, 32, 64);
    float acc[8];
#pragma unroll
    for (int k = 0; k < 4; ++k) { acc[2 * k] = acc2[k].x; acc[2 * k + 1] = acc2[k].y; }
#pragma unroll
    for (int c = 0; c < 8; ++c) {
        acc[c] += __shfl_xor(acc[c], 8, 64);
        acc[c] += __shfl_xor(acc[c], 16, 64);
        acc[c] += __shfl_xor(acc[c], 32, 64);
    }
    float inv = 1.0f / den;
    float r0 = 0.0f, r1 = 0.0f;
#pragma unroll
    for (int c = 0; c < 8; ++c) {
        int col = (h << 3) + c;
        float v = fmaf(acc[c], inv, sB1[col]);
        v = v > 0.0f ? v : expm1f(v);    // ELU
        r0 = fmaf(v, sW2[col * 2 + 0], r0);
        r1 = fmaf(v, sW2[col * 2 + 1], r1);
    }
    // sum over h (lane bits 0..2)
    r0 += __shfl_xor(r0, 1, 64); r0 += __shfl_xor(r0, 2, 64); r0 += __shfl_xor(r0, 4, 64);
    r1 += __shfl_xor(r1, 1, 64); r1 += __shfl_xor(r1, 2, 64); r1 += __shfl_xor(r1, 4, 64);
    if (l == 0) {
        // packed node record for layer 2: (a_s2, a_d2, h2_0, h2_1)
        p2[n] = make_float4(r0 * sA2[0] + r1 * sA2[1],
                            r0 * sA2[2] + r1 * sA2[3], r0, r1);
    }
}

// ---------------- layer 2: 16 lanes per node, single 16B gather ----------------

__global__ void k_gat2(const int* __restrict__ ptr, const int* __restrict__ srcs,
                       const float4* __restrict__ p2, const float* __restrict__ b2,
                       float* __restrict__ out, int N) {
    int t = blockIdx.x * blockDim.x + threadIdx.x;
    int n = t >> 4;
    if (n >= N) return;
    int l = threadIdx.x & 15;
    int start = ptr[n], end = ptr[n + 1];
    float ad = p2[n].y;
    float den = 0.0f, a0 = 0.0f, a1 = 0.0f;
    for (int idx = start + l; idx < end; idx += 16) {
        int s = srcs[idx];
        float4 ps = p2[s];
        float ex = exp2f(fmaf(lrelu(ps.x + ad), LOG2E, SHBIAS));
        den += ex;
        a0 = fmaf(ex, ps.z, a0);
        a1 = fmaf(ex, ps.w, a1);
    }
#pragma unroll
    for (int off = 8; off; off >>= 1) {
        den += __shfl_xor(den, off, 16);
        a0  += __shfl_xor(a0, off, 16);
        a1  += __shfl_xor(a1, off, 16);
    }
    if (l == 0) {
        float inv = 1.0f / den;
        float o0 = a0 * inv + b2[0];
        float o1 = a1 * inv + b2[1];
        float mx = fmaxf(o0, o1);
        float lse = mx + logf(__expf(o0 - mx) + __expf(o1 - mx));
        out[n * 2 + 0] = o0 - lse;
        out[n * 2 + 1] = o1 - lse;
    }
}

extern "C" void kernel_launch(void* const* d_in, const int* in_sizes, int n_in,
                              void* d_out, int out_size, void* d_ws, size_t ws_size,
                              hipStream_t stream) {
    const float* x   = (const float*)d_in[0];
    const int*   ei  = (const int*)d_in[1];
    const float* W1  = (const float*)d_in[2];
    const float* as1 = (const float*)d_in[3];
    const float* ad1 = (const float*)d_in[4];
    const float* b1  = (const float*)d_in[5];
    const float* W2  = (const float*)d_in[6];
    const float* as2 = (const float*)d_in[7];
    const float* ad2 = (const float*)d_in[8];
    const float* b2  = (const float*)d_in[9];
    float* out = (float*)d_out;

    const int N  = in_sizes[0] / F_IN;   // 100000
    const int E  = in_sizes[1] / 2;      // 3200000
    const int E4 = E / 4;                // 800000
    const int Et = E + N;
    const int nbk = (N + 255) >> 8;      // 391 buckets
    const int GA  = (E4 + 2047) >> 11;   // 391 edge-chunk blocks (8192 edges each)
    const int F   = nbk * GA;            // 152881 flat scan size
    const int nbScan = (F + 255) >> 8;   // 598 (<=1024)

    char* p = (char*)d_ws;
    ushort_t* h1b = (ushort_t*)p; p += (size_t)N * D1 * 2;   // bf16 h1 (12.8MB, 16B aligned)
    float4* p2  = (float4*)p; p += (size_t)N * 16;           // packed layer-2 node record
    float* a_s1 = (float*)p; p += (size_t)N * NH * 4;
    float* a_d1 = (float*)p; p += (size_t)N * NH * 4;
    int* blkcnt = (int*)p;   p += (size_t)F * 4;
    int* tmp    = (int*)p;   p += (size_t)nbScan * 256 * 4;
    int* bsum   = (int*)p;   p += (size_t)nbScan * 4;
    int* excl   = (int*)p;   p += (size_t)(F + 1) * 4;
    int* partbuf= (int*)p;   p += (size_t)E * 4;
    int* ptr    = (int*)p;   p += (size_t)(N + 1) * 4;
    int* srcs   = (int*)p;   p += (size_t)Et * 4;

    const int nN1 = (N * NH + 255) / 256;    // 3125 node1 blocks

    hipLaunchKernelGGL(k_bhist_node1, dim3(GA + nN1), dim3(256), 0, stream,
                       ei, E4, GA, nbk, blkcnt, x, W1, as1, ad1, h1b, a_s1, a_d1, N);

    hipLaunchKernelGGL(k_scan_block, dim3(nbScan), dim3(256), 0, stream, blkcnt, tmp, bsum, F);
    hipLaunchKernelGGL(k_scan_bsums1024, dim3(1), dim3(1024), 0, stream, bsum, nbScan);
    hipLaunchKernelGGL(k_scan_fin, dim3((F + 256) / 256), dim3(256), 0, stream,
                       tmp, bsum, excl, F, E);

    hipLaunchKernelGGL(k_part, dim3(GA), dim3(256), 0, stream, ei, E4, GA, nbk, excl, partbuf);

    hipLaunchKernelGGL(k_csr, dim3(nbk), dim3(256), 0, stream,
                       excl, partbuf, ptr, srcs, N, GA, nbk, Et);

    hipLaunchKernelGGL(k_gat1, dim3((N + 3) / 4), dim3(256), 0, stream,
                       ptr, srcs, a_s1, a_d1, h1b, b1, W2, as2, ad2, p2, N);

    hipLaunchKernelGGL(k_gat2, dim3((N * 16 + 255) / 256), dim3(256), 0, stream,
                       ptr, srcs, p2, b2, out, N);
}